// Round 3
// baseline (304.378 us; speedup 1.0000x reference)
//
#include <hip/hip_runtime.h>
#include <hip/hip_bf16.h>
#include <stdint.h>

// ViewLoRALinear: out[25088,1024] = x@W^T + b + (x@A_v)@B_v, fp32 in/out.
// No fp32 MFMA on CDNA4 -> cast x,W to bf16 (RNE) in d_ws (streaming kernel),
// h = x@A_v coalesced rank-4 kernel, then m97-structure bf16 MFMA GEMM with
// fp32 accum + fused bias/LoRA epilogue (view-uniform fast path) + XCD swizzle.
#define M_TOT 25088
#define N_TOT 1024
#define K_TOT 1024
#define T_LEN 196
#define NVIEW 11
#define ROWS_PER_VIEW 1568   // 8 frames * 196 tokens per view_idx entry

#define BM 128
#define BN 128
#define BK 64

typedef unsigned short u16;
typedef __bf16 bf16x8 __attribute__((ext_vector_type(8)));
typedef float f32x4 __attribute__((ext_vector_type(4)));
typedef unsigned short u16x8 __attribute__((ext_vector_type(8)));

// ws layout (fast path): [x_bf16: 25088*1024 u16][W_bf16: 1024*1024 u16][h: 25088*4 f32]
#define XB_ELEMS ((size_t)M_TOT * K_TOT)              // 25,690,112
#define WB_ELEMS ((size_t)N_TOT * K_TOT)              // 1,048,576
#define WB_OFF_B (XB_ELEMS * 2)
#define H_OFF_B  (WB_OFF_B + WB_ELEMS * 2)
#define WS_NEEDED (H_OFF_B + (size_t)M_TOT * 4 * 4)

__device__ __forceinline__ u16 f2bf(float f) {
    union { float f; unsigned int i; } c; c.f = f;
    unsigned int i = c.i;
    return (u16)((i + 0x7FFFu + ((i >> 16) & 1u)) >> 16);  // RNE (finite inputs)
}
__device__ __forceinline__ float bf2f(unsigned int u) {
    union { unsigned int i; float f; } c; c.i = u << 16; return c.f;
}

// ---------------------------------------------------------------------------
// Kernel 1: pure streaming fp32 -> bf16 cast of x and W into ws.
// 8 elems/thread; both regions 8-divisible so no thread straddles.
// ---------------------------------------------------------------------------
__global__ __launch_bounds__(256) void cast_kernel(
    const float* __restrict__ x, const float* __restrict__ W,
    u16* __restrict__ xb, u16* __restrict__ wb) {
    const size_t e = ((size_t)blockIdx.x * 256 + threadIdx.x) * 8;
    const float* src;
    u16* dst;
    if (e < XB_ELEMS) { src = x + e; dst = xb + e; }
    else              { src = W + (e - XB_ELEMS); dst = wb + (e - XB_ELEMS); }
    float4 v0 = *(const float4*)src;
    float4 v1 = *(const float4*)(src + 4);
    u16x8 o = { f2bf(v0.x), f2bf(v0.y), f2bf(v0.z), f2bf(v0.w),
                f2bf(v1.x), f2bf(v1.y), f2bf(v1.z), f2bf(v1.w) };
    *(u16x8*)dst = o;
}

// ---------------------------------------------------------------------------
// Kernel 2: h[row][0..3] = sum_k xb[row,k] * A_v[k,r].  One wave per row.
// Lane i owns k = it*128 + 2i {+0,+1}: xb load is 4B/lane coalesced,
// A loads are two float4 at 32B/lane stride -> fully coalesced.
// ---------------------------------------------------------------------------
__global__ __launch_bounds__(256) void h_kernel(
    const u16* __restrict__ xb, const int* __restrict__ view_idx,
    const float* __restrict__ lora_A, float* __restrict__ h) {
    const int row  = blockIdx.x * 4 + (threadIdx.x >> 6);
    const int lane = threadIdx.x & 63;
    int v = view_idx[row / ROWS_PER_VIEW];
    v = v < 0 ? 0 : (v > NVIEW - 1 ? NVIEW - 1 : v);
    const float* A = lora_A + (size_t)v * (K_TOT * 4);
    const unsigned int* xr = (const unsigned int*)(xb + (size_t)row * K_TOT);

    float a0 = 0.f, a1 = 0.f, a2 = 0.f, a3 = 0.f;
#pragma unroll
    for (int it = 0; it < 8; ++it) {
        unsigned int p = xr[it * 64 + lane];
        float x0 = bf2f(p & 0xffffu);
        float x1 = bf2f(p >> 16);
        const int k = it * 128 + lane * 2;
        float4 av0 = *(const float4*)(A + (size_t)k * 4);
        float4 av1 = *(const float4*)(A + (size_t)k * 4 + 4);
        a0 += x0 * av0.x + x1 * av1.x;
        a1 += x0 * av0.y + x1 * av1.y;
        a2 += x0 * av0.z + x1 * av1.z;
        a3 += x0 * av0.w + x1 * av1.w;
    }
#pragma unroll
    for (int off = 32; off > 0; off >>= 1) {
        a0 += __shfl_xor(a0, off, 64);
        a1 += __shfl_xor(a1, off, 64);
        a2 += __shfl_xor(a2, off, 64);
        a3 += __shfl_xor(a3, off, 64);
    }
    if (lane == 0)
        *(float4*)(h + (size_t)row * 4) = make_float4(a0, a1, a2, a3);
}

// Fallback h (ws too small): fp32 x, one wave/row, same coalesced scheme.
__global__ __launch_bounds__(256) void h_only_kernel(
    const float* __restrict__ x, const int* __restrict__ view_idx,
    const float* __restrict__ lora_A, float* __restrict__ h) {
    const int row  = blockIdx.x * 4 + (threadIdx.x >> 6);
    const int lane = threadIdx.x & 63;
    int v = view_idx[row / ROWS_PER_VIEW];
    v = v < 0 ? 0 : (v > NVIEW - 1 ? NVIEW - 1 : v);
    const float* A  = lora_A + (size_t)v * (K_TOT * 4);
    const float* xr = x + (size_t)row * K_TOT;
    float a0 = 0.f, a1 = 0.f, a2 = 0.f, a3 = 0.f;
#pragma unroll
    for (int it = 0; it < 16; ++it) {
        const int k = it * 64 + lane;
        float xf = xr[k];
        float4 av = *(const float4*)(A + (size_t)k * 4);
        a0 += xf * av.x; a1 += xf * av.y; a2 += xf * av.z; a3 += xf * av.w;
    }
#pragma unroll
    for (int off = 32; off > 0; off >>= 1) {
        a0 += __shfl_xor(a0, off, 64);
        a1 += __shfl_xor(a1, off, 64);
        a2 += __shfl_xor(a2, off, 64);
        a3 += __shfl_xor(a3, off, 64);
    }
    if (lane == 0)
        *(float4*)(h + (size_t)row * 4) = make_float4(a0, a1, a2, a3);
}

// ---------------------------------------------------------------------------
// Kernel 3: m97-structure GEMM C = X*W^T + bias + h*B_v, fp32 out.
// 1D grid with XCD swizzle: each XCD sweeps all 8 bx of one by, so its L2
// fetches the 256KB A-tile once (W is 2MB, L2-resident).
// ---------------------------------------------------------------------------
template <bool CONV>
__global__ __launch_bounds__(256) void gemm_lora_kernel(
    const void* __restrict__ xp, const void* __restrict__ Wp,
    const float* __restrict__ bias, const int* __restrict__ view_idx,
    const float* __restrict__ lora_B, const float* __restrict__ h,
    float* __restrict__ out) {
    __shared__ u16 As[BM * BK];   // 16 KB [BM][BK] bf16
    __shared__ u16 Bs[BN * BK];   // 16 KB [BN][BK] bf16

    const int tid = threadIdx.x;
    // XCD-aware decode: xcd = id%8 (round-robin). Within a 64-id chunk, XCD x
    // gets ids w%8==x -> by = c*8 + x (constant per XCD), bx = w>>3 (0..7).
    const int id = blockIdx.x;
    int bx, by;
    if (id < 1536) { const int c = id >> 6, w = id & 63; by = c * 8 + (w & 7); bx = w >> 3; }
    else           { const int r = id - 1536; by = 192 + (r & 3); bx = r >> 2; }

    const int lane = tid & 63;
    const int wave = tid >> 6;
    const int wm   = (wave >> 1) * 64;
    const int wn   = (wave & 1) * 64;
    const int l16  = lane & 15;
    const int quad = lane >> 4;

    const size_t a_base = (size_t)(by * BM) * K_TOT;
    const size_t b_base = (size_t)(bx * BN) * K_TOT;

    f32x4 acc[4][4] = {};

    for (int kt = 0; kt < K_TOT / BK; ++kt) {
        const int kofs = kt * BK;
        if constexpr (!CONV) {
            const u16* x = (const u16*)xp;
            const u16* W = (const u16*)Wp;
#pragma unroll
            for (int i = 0; i < 4; ++i) {
                const int e = i * 2048 + tid * 8;   // LDS byte = 2e = wave-base + lane*16
                const int r = e >> 6, c = e & 63;
                __builtin_amdgcn_global_load_lds(
                    (const __attribute__((address_space(1))) void*)(x + a_base + (size_t)r * K_TOT + kofs + c),
                    (__attribute__((address_space(3))) void*)(As + e), 16, 0, 0);
                __builtin_amdgcn_global_load_lds(
                    (const __attribute__((address_space(1))) void*)(W + b_base + (size_t)r * K_TOT + kofs + c),
                    (__attribute__((address_space(3))) void*)(Bs + e), 16, 0, 0);
            }
        } else {
            const float* x = (const float*)xp;
            const float* W = (const float*)Wp;
#pragma unroll
            for (int i = 0; i < 8; ++i) {
                const int e = i * 1024 + tid * 4;
                const int r = e >> 6, c = e & 63;
                float4 av = *(const float4*)(x + a_base + (size_t)r * K_TOT + kofs + c);
                float4 bv = *(const float4*)(W + b_base + (size_t)r * K_TOT + kofs + c);
                *(u16*)(As + e)     = f2bf(av.x); *(u16*)(As + e + 1) = f2bf(av.y);
                *(u16*)(As + e + 2) = f2bf(av.z); *(u16*)(As + e + 3) = f2bf(av.w);
                *(u16*)(Bs + e)     = f2bf(bv.x); *(u16*)(Bs + e + 1) = f2bf(bv.y);
                *(u16*)(Bs + e + 2) = f2bf(bv.z); *(u16*)(Bs + e + 3) = f2bf(bv.w);
            }
        }
        __syncthreads();
#pragma unroll
        for (int kk = 0; kk < 2; ++kk) {
            const int k0 = kk * 32 + quad * 8;
            bf16x8 a_frag[4], b_frag[4];
#pragma unroll
            for (int mi = 0; mi < 4; ++mi)
                a_frag[mi] = *(const bf16x8*)(const void*)(As + (wm + mi * 16 + l16) * BK + k0);
#pragma unroll
            for (int ni = 0; ni < 4; ++ni)
                b_frag[ni] = *(const bf16x8*)(const void*)(Bs + (wn + ni * 16 + l16) * BK + k0);
#pragma unroll
            for (int mi = 0; mi < 4; ++mi)
#pragma unroll
                for (int ni = 0; ni < 4; ++ni)
                    acc[mi][ni] = __builtin_amdgcn_mfma_f32_16x16x32_bf16(
                        a_frag[mi], b_frag[ni], acc[mi][ni], 0, 0, 0);
        }
        __syncthreads();
    }

    // Epilogue. C/D layout (m89): col = lane&15, row = quad*4 + reg.
    const int rowBase = by * BM + wm;
    const int colBase = bx * BN + wn;
    float biasv[4];
#pragma unroll
    for (int ni = 0; ni < 4; ++ni) biasv[ni] = bias[colBase + ni * 16 + l16];

    const int ve0 = (by * BM) / ROWS_PER_VIEW;
    const int ve1 = (by * BM + BM - 1) / ROWS_PER_VIEW;
    if (ve0 == ve1) {
        // View-uniform tile (192 of 196): hoist B_v into registers.
        int v = view_idx[ve0];
        v = v < 0 ? 0 : (v > NVIEW - 1 ? NVIEW - 1 : v);
        const float* Bv = lora_B + (size_t)v * (4 * N_TOT);
        float Bvv[4][4];
#pragma unroll
        for (int r = 0; r < 4; ++r)
#pragma unroll
            for (int ni = 0; ni < 4; ++ni)
                Bvv[r][ni] = Bv[r * N_TOT + colBase + ni * 16 + l16];
#pragma unroll
        for (int mi = 0; mi < 4; ++mi) {
#pragma unroll
            for (int reg = 0; reg < 4; ++reg) {
                const int grow = rowBase + mi * 16 + quad * 4 + reg;
                const float4 hv = *(const float4*)(h + (size_t)grow * 4);
                float* orow = out + (size_t)grow * N_TOT;
#pragma unroll
                for (int ni = 0; ni < 4; ++ni) {
                    float lora = hv.x * Bvv[0][ni] + hv.y * Bvv[1][ni]
                               + hv.z * Bvv[2][ni] + hv.w * Bvv[3][ni];
                    orow[colBase + ni * 16 + l16] = acc[mi][ni][reg] + biasv[ni] + lora;
                }
            }
        }
    } else {
#pragma unroll
        for (int mi = 0; mi < 4; ++mi) {
#pragma unroll
            for (int reg = 0; reg < 4; ++reg) {
                const int grow = rowBase + mi * 16 + quad * 4 + reg;
                int v = view_idx[grow / ROWS_PER_VIEW];
                v = v < 0 ? 0 : (v > NVIEW - 1 ? NVIEW - 1 : v);
                const float4 hv = *(const float4*)(h + (size_t)grow * 4);
                const float* Bv = lora_B + (size_t)v * (4 * N_TOT);
                float* orow = out + (size_t)grow * N_TOT;
#pragma unroll
                for (int ni = 0; ni < 4; ++ni) {
                    const int gcol = colBase + ni * 16 + l16;
                    float lora = hv.x * Bv[gcol]
                               + hv.y * Bv[N_TOT + gcol]
                               + hv.z * Bv[2 * N_TOT + gcol]
                               + hv.w * Bv[3 * N_TOT + gcol];
                    orow[gcol] = acc[mi][ni][reg] + biasv[ni] + lora;
                }
            }
        }
    }
}

extern "C" void kernel_launch(void* const* d_in, const int* in_sizes, int n_in,
                              void* d_out, int out_size, void* d_ws, size_t ws_size,
                              hipStream_t stream) {
    const float* x        = (const float*)d_in[0];
    const int*   view_idx = (const int*)d_in[1];
    const float* W        = (const float*)d_in[2];
    const float* b        = (const float*)d_in[3];
    const float* lora_A   = (const float*)d_in[4];
    const float* lora_B   = (const float*)d_in[5];
    float* out = (float*)d_out;

    const dim3 ggrid((M_TOT / BM) * (N_TOT / BN));  // 1568, XCD-swizzled in-kernel
    if (ws_size >= WS_NEEDED) {
        u16*   xb = (u16*)d_ws;
        u16*   wb = (u16*)((char*)d_ws + WB_OFF_B);
        float* h  = (float*)((char*)d_ws + H_OFF_B);
        const int cast_blocks = (int)((XB_ELEMS + WB_ELEMS) / (8 * 256));  // 13056
        hipLaunchKernelGGL(cast_kernel, dim3(cast_blocks), dim3(256), 0, stream, x, W, xb, wb);
        hipLaunchKernelGGL(h_kernel, dim3(M_TOT / 4), dim3(256), 0, stream, xb, view_idx, lora_A, h);
        hipLaunchKernelGGL((gemm_lora_kernel<false>), ggrid, dim3(256), 0, stream,
                           xb, wb, b, view_idx, lora_B, h, out);
    } else {
        float* h = (float*)d_ws;  // 401,408 B
        hipLaunchKernelGGL(h_only_kernel, dim3(M_TOT / 4), dim3(256), 0, stream,
                           x, view_idx, lora_A, h);
        hipLaunchKernelGGL((gemm_lora_kernel<true>), ggrid, dim3(256), 0, stream,
                           x, W, b, view_idx, lora_B, h, out);
    }
}

// Round 4
// 275.929 us; speedup vs baseline: 1.1031x; 1.1031x over previous
//
#include <hip/hip_runtime.h>
#include <hip/hip_bf16.h>
#include <stdint.h>

// ViewLoRALinear: out[25088,1024] = x@W^T + b + (x@A_v)@B_v, fp32 in/out.
// No fp32 MFMA on CDNA4 -> cast x,W to bf16 (RNE) in d_ws + h=x@A_v (one prep
// kernel), then m97-structure bf16 MFMA GEMM (fp32 accum) with XOR-swizzled
// LDS (kills the 16-way ds_read_b128 bank conflicts: row stride 128B = 32
// banks; swizzle spreads chunks), XCD-aware block swizzle, fused epilogue.
#define M_TOT 25088
#define N_TOT 1024
#define K_TOT 1024
#define T_LEN 196
#define NVIEW 11
#define ROWS_PER_VIEW 1568   // 8 frames * 196 tokens per view_idx entry

#define BM 128
#define BN 128
#define BK 64

typedef unsigned short u16;
typedef __bf16 bf16x8 __attribute__((ext_vector_type(8)));
typedef float f32x4 __attribute__((ext_vector_type(4)));
typedef unsigned short u16x4 __attribute__((ext_vector_type(4)));

// ws layout (fast path): [x_bf16: 25088*1024 u16][W_bf16: 1024*1024 u16][h: 25088*4 f32]
#define XB_ELEMS ((size_t)M_TOT * K_TOT)
#define WB_ELEMS ((size_t)N_TOT * K_TOT)
#define WB_OFF_B (XB_ELEMS * 2)
#define H_OFF_B  (WB_OFF_B + WB_ELEMS * 2)
#define WS_NEEDED (H_OFF_B + (size_t)M_TOT * 4 * 4)

__device__ __forceinline__ u16 f2bf(float f) {
    union { float f; unsigned int i; } c; c.f = f;
    unsigned int i = c.i;
    return (u16)((i + 0x7FFFu + ((i >> 16) & 1u)) >> 16);  // RNE (finite inputs)
}

// ---------------------------------------------------------------------------
// Kernel 1: prep. Blocks 0..6271: one x-row per wave -> bf16 cast + h[row].
// Blocks 6272..6527: one W-row per wave -> bf16 cast.
// h uses lane->k = it*128 + 2*lane mapping so A float4 loads are coalesced
// (32B/lane stride); x re-read for h is an L1 hit.
// ---------------------------------------------------------------------------
__global__ __launch_bounds__(256) void prep_kernel(
    const float* __restrict__ x, const float* __restrict__ W,
    const int* __restrict__ view_idx, const float* __restrict__ lora_A,
    u16* __restrict__ xb, u16* __restrict__ wb, float* __restrict__ h) {
    const int wave = threadIdx.x >> 6;
    const int lane = threadIdx.x & 63;
    const int blk  = blockIdx.x;

    if (blk >= M_TOT / 4) {  // W cast
        const int row = (blk - M_TOT / 4) * 4 + wave;
        const float* src = W + (size_t)row * K_TOT;
        u16* dst = wb + (size_t)row * K_TOT;
#pragma unroll
        for (int it = 0; it < 4; ++it) {
            const int k = it * 256 + lane * 4;
            float4 v = *(const float4*)(src + k);
            u16x4 o = { f2bf(v.x), f2bf(v.y), f2bf(v.z), f2bf(v.w) };
            *(u16x4*)(dst + k) = o;
        }
        return;
    }

    const int row = blk * 4 + wave;
    int v = view_idx[row / ROWS_PER_VIEW];
    v = v < 0 ? 0 : (v > NVIEW - 1 ? NVIEW - 1 : v);
    const float* A  = lora_A + (size_t)v * (K_TOT * 4);
    const float* xr = x + (size_t)row * K_TOT;
    u16* dst = xb + (size_t)row * K_TOT;

    // cast pass (coalesced float4 loads / 8B stores)
#pragma unroll
    for (int it = 0; it < 4; ++it) {
        const int k = it * 256 + lane * 4;
        float4 xv = *(const float4*)(xr + k);
        u16x4 o = { f2bf(xv.x), f2bf(xv.y), f2bf(xv.z), f2bf(xv.w) };
        *(u16x4*)(dst + k) = o;
    }
    // h pass (x re-read from L1 at h-friendly mapping; A fully coalesced)
    float a0 = 0.f, a1 = 0.f, a2 = 0.f, a3 = 0.f;
#pragma unroll
    for (int it = 0; it < 8; ++it) {
        const int k = it * 128 + lane * 2;
        float2 xv = *(const float2*)(xr + k);
        float4 av0 = *(const float4*)(A + (size_t)k * 4);
        float4 av1 = *(const float4*)(A + (size_t)k * 4 + 4);
        a0 += xv.x * av0.x + xv.y * av1.x;
        a1 += xv.x * av0.y + xv.y * av1.y;
        a2 += xv.x * av0.z + xv.y * av1.z;
        a3 += xv.x * av0.w + xv.y * av1.w;
    }
#pragma unroll
    for (int off = 32; off > 0; off >>= 1) {
        a0 += __shfl_xor(a0, off, 64);
        a1 += __shfl_xor(a1, off, 64);
        a2 += __shfl_xor(a2, off, 64);
        a3 += __shfl_xor(a3, off, 64);
    }
    if (lane == 0)
        *(float4*)(h + (size_t)row * 4) = make_float4(a0, a1, a2, a3);
}

// Fallback h (ws too small): fp32 x, one wave/row.
__global__ __launch_bounds__(256) void h_only_kernel(
    const float* __restrict__ x, const int* __restrict__ view_idx,
    const float* __restrict__ lora_A, float* __restrict__ h) {
    const int row  = blockIdx.x * 4 + (threadIdx.x >> 6);
    const int lane = threadIdx.x & 63;
    int v = view_idx[row / ROWS_PER_VIEW];
    v = v < 0 ? 0 : (v > NVIEW - 1 ? NVIEW - 1 : v);
    const float* A  = lora_A + (size_t)v * (K_TOT * 4);
    const float* xr = x + (size_t)row * K_TOT;
    float a0 = 0.f, a1 = 0.f, a2 = 0.f, a3 = 0.f;
#pragma unroll
    for (int it = 0; it < 8; ++it) {
        const int k = it * 128 + lane * 2;
        float2 xv = *(const float2*)(xr + k);
        float4 av0 = *(const float4*)(A + (size_t)k * 4);
        float4 av1 = *(const float4*)(A + (size_t)k * 4 + 4);
        a0 += xv.x * av0.x + xv.y * av1.x;
        a1 += xv.x * av0.y + xv.y * av1.y;
        a2 += xv.x * av0.z + xv.y * av1.z;
        a3 += xv.x * av0.w + xv.y * av1.w;
    }
#pragma unroll
    for (int off = 32; off > 0; off >>= 1) {
        a0 += __shfl_xor(a0, off, 64);
        a1 += __shfl_xor(a1, off, 64);
        a2 += __shfl_xor(a2, off, 64);
        a3 += __shfl_xor(a3, off, 64);
    }
    if (lane == 0)
        *(float4*)(h + (size_t)row * 4) = make_float4(a0, a1, a2, a3);
}

// ---------------------------------------------------------------------------
// Kernel 2: GEMM C = X*W^T + bias + h*B_v, fp32 out.
// LDS layout XOR-swizzled: slot (row r, chunk c) holds global chunk c^(r&7)
// (chunk = 8 elems = 16B). global_load_lds keeps its contiguous lane*16 dst;
// the permutation is applied to the SOURCE address. Fragment ds_read_b128
// applies the same XOR -> conflicts drop 16-way -> ~2-way (free).
// ---------------------------------------------------------------------------
template <bool CONV>
__global__ __launch_bounds__(256) void gemm_lora_kernel(
    const void* __restrict__ xp, const void* __restrict__ Wp,
    const float* __restrict__ bias, const int* __restrict__ view_idx,
    const float* __restrict__ lora_B, const float* __restrict__ h,
    float* __restrict__ out) {
    __shared__ u16 As[BM * BK];   // 16 KB [BM][BK(swizzled)] bf16
    __shared__ u16 Bs[BN * BK];

    const int tid = threadIdx.x;
    // XCD swizzle: xcd = id%8; XCD x sweeps all 8 bx of by = c*8 + x.
    const int id = blockIdx.x;
    int bx, by;
    if (id < 1536) { const int c = id >> 6, w = id & 63; by = c * 8 + (w & 7); bx = w >> 3; }
    else           { const int r = id - 1536; by = 192 + (r & 3); bx = r >> 2; }

    const int lane = tid & 63;
    const int wave = tid >> 6;
    const int wm   = (wave >> 1) * 64;
    const int wn   = (wave & 1) * 64;
    const int l16  = lane & 15;
    const int quad = lane >> 4;
    const int sw   = l16 & 7;           // fragment-read XOR key

    const size_t a_base = (size_t)(by * BM) * K_TOT;
    const size_t b_base = (size_t)(bx * BN) * K_TOT;

    f32x4 acc[4][4] = {};

    for (int kt = 0; kt < K_TOT / BK; ++kt) {
        const int kofs = kt * BK;
        if constexpr (!CONV) {
            const u16* x = (const u16*)xp;
            const u16* W = (const u16*)Wp;
#pragma unroll
            for (int i = 0; i < 4; ++i) {
                const int e = i * 2048 + tid * 8;          // LDS dst elem (contiguous)
                const int r = e >> 6;                      // tile row
                const int c = (((tid & 7) ^ (r & 7)) << 3); // swizzled SOURCE chunk
                __builtin_amdgcn_global_load_lds(
                    (const __attribute__((address_space(1))) void*)(x + a_base + (size_t)r * K_TOT + kofs + c),
                    (__attribute__((address_space(3))) void*)(As + e), 16, 0, 0);
                __builtin_amdgcn_global_load_lds(
                    (const __attribute__((address_space(1))) void*)(W + b_base + (size_t)r * K_TOT + kofs + c),
                    (__attribute__((address_space(3))) void*)(Bs + e), 16, 0, 0);
            }
        } else {
            const float* x = (const float*)xp;
            const float* W = (const float*)Wp;
#pragma unroll
            for (int i = 0; i < 8; ++i) {
                const int e = i * 1024 + tid * 4;
                const int r = e >> 6, o = e & 63;
                const int d = r * 64 + (((o >> 3) ^ (r & 7)) << 3) + (o & 7); // swizzled dst
                float4 av = *(const float4*)(x + a_base + (size_t)r * K_TOT + kofs + o);
                float4 bv = *(const float4*)(W + b_base + (size_t)r * K_TOT + kofs + o);
                u16x4 ao = { f2bf(av.x), f2bf(av.y), f2bf(av.z), f2bf(av.w) };
                u16x4 bo = { f2bf(bv.x), f2bf(bv.y), f2bf(bv.z), f2bf(bv.w) };
                *(u16x4*)(As + d) = ao;
                *(u16x4*)(Bs + d) = bo;
            }
        }
        __syncthreads();
#pragma unroll
        for (int kk = 0; kk < 2; ++kk) {
            const int csw = (((kk * 4 + quad) ^ sw) << 3);  // swizzled chunk offset
            bf16x8 a_frag[4], b_frag[4];
#pragma unroll
            for (int mi = 0; mi < 4; ++mi)
                a_frag[mi] = *(const bf16x8*)(const void*)(As + (wm + mi * 16 + l16) * BK + csw);
#pragma unroll
            for (int ni = 0; ni < 4; ++ni)
                b_frag[ni] = *(const bf16x8*)(const void*)(Bs + (wn + ni * 16 + l16) * BK + csw);
#pragma unroll
            for (int mi = 0; mi < 4; ++mi)
#pragma unroll
                for (int ni = 0; ni < 4; ++ni)
                    acc[mi][ni] = __builtin_amdgcn_mfma_f32_16x16x32_bf16(
                        a_frag[mi], b_frag[ni], acc[mi][ni], 0, 0, 0);
        }
        __syncthreads();
    }

    // Epilogue. C/D layout (m89): col = lane&15, row = quad*4 + reg.
    const int rowBase = by * BM + wm;
    const int colBase = bx * BN + wn;
    float biasv[4];
#pragma unroll
    for (int ni = 0; ni < 4; ++ni) biasv[ni] = bias[colBase + ni * 16 + l16];

    const int ve0 = (by * BM) / ROWS_PER_VIEW;
    const int ve1 = (by * BM + BM - 1) / ROWS_PER_VIEW;
    if (ve0 == ve1) {
        int v = view_idx[ve0];
        v = v < 0 ? 0 : (v > NVIEW - 1 ? NVIEW - 1 : v);
        const float* Bv = lora_B + (size_t)v * (4 * N_TOT);
        float Bvv[4][4];
#pragma unroll
        for (int r = 0; r < 4; ++r)
#pragma unroll
            for (int ni = 0; ni < 4; ++ni)
                Bvv[r][ni] = Bv[r * N_TOT + colBase + ni * 16 + l16];
#pragma unroll
        for (int mi = 0; mi < 4; ++mi) {
#pragma unroll
            for (int reg = 0; reg < 4; ++reg) {
                const int grow = rowBase + mi * 16 + quad * 4 + reg;
                const float4 hv = *(const float4*)(h + (size_t)grow * 4);
                float* orow = out + (size_t)grow * N_TOT;
#pragma unroll
                for (int ni = 0; ni < 4; ++ni) {
                    float lora = hv.x * Bvv[0][ni] + hv.y * Bvv[1][ni]
                               + hv.z * Bvv[2][ni] + hv.w * Bvv[3][ni];
                    orow[colBase + ni * 16 + l16] = acc[mi][ni][reg] + biasv[ni] + lora;
                }
            }
        }
    } else {
#pragma unroll
        for (int mi = 0; mi < 4; ++mi) {
#pragma unroll
            for (int reg = 0; reg < 4; ++reg) {
                const int grow = rowBase + mi * 16 + quad * 4 + reg;
                int v = view_idx[grow / ROWS_PER_VIEW];
                v = v < 0 ? 0 : (v > NVIEW - 1 ? NVIEW - 1 : v);
                const float4 hv = *(const float4*)(h + (size_t)grow * 4);
                const float* Bv = lora_B + (size_t)v * (4 * N_TOT);
                float* orow = out + (size_t)grow * N_TOT;
#pragma unroll
                for (int ni = 0; ni < 4; ++ni) {
                    const int gcol = colBase + ni * 16 + l16;
                    float lora = hv.x * Bv[gcol]
                               + hv.y * Bv[N_TOT + gcol]
                               + hv.z * Bv[2 * N_TOT + gcol]
                               + hv.w * Bv[3 * N_TOT + gcol];
                    orow[gcol] = acc[mi][ni][reg] + biasv[ni] + lora;
                }
            }
        }
    }
}

extern "C" void kernel_launch(void* const* d_in, const int* in_sizes, int n_in,
                              void* d_out, int out_size, void* d_ws, size_t ws_size,
                              hipStream_t stream) {
    const float* x        = (const float*)d_in[0];
    const int*   view_idx = (const int*)d_in[1];
    const float* W        = (const float*)d_in[2];
    const float* b        = (const float*)d_in[3];
    const float* lora_A   = (const float*)d_in[4];
    const float* lora_B   = (const float*)d_in[5];
    float* out = (float*)d_out;

    const dim3 ggrid((M_TOT / BM) * (N_TOT / BN));  // 1568, swizzled in-kernel
    if (ws_size >= WS_NEEDED) {
        u16*   xb = (u16*)d_ws;
        u16*   wb = (u16*)((char*)d_ws + WB_OFF_B);
        float* h  = (float*)((char*)d_ws + H_OFF_B);
        hipLaunchKernelGGL(prep_kernel, dim3(M_TOT / 4 + N_TOT / 4), dim3(256), 0, stream,
                           x, W, view_idx, lora_A, xb, wb, h);
        hipLaunchKernelGGL((gemm_lora_kernel<false>), ggrid, dim3(256), 0, stream,
                           xb, wb, b, view_idx, lora_B, h, out);
    } else {
        float* h = (float*)d_ws;  // 401,408 B
        hipLaunchKernelGGL(h_only_kernel, dim3(M_TOT / 4), dim3(256), 0, stream,
                           x, view_idx, lora_A, h);
        hipLaunchKernelGGL((gemm_lora_kernel<true>), ggrid, dim3(256), 0, stream,
                           x, W, b, view_idx, lora_B, h, out);
    }
}